// Round 8
// baseline (188.761 us; speedup 1.0000x reference)
//
#include <hip/hip_runtime.h>

// YOLOv7 P3 head (stride 8): B=16, A=3, NC=80, H=W=80.
// Input  (b, a*85, h, w) channel-major fp32.
// Output (b, a*h*w, 85)  fp32: [px,py,pw,ph,conf,cls*80].
//
// v9: persistent pipelined blocks. v1-v8 pinned at 2.35-2.65 TB/s for
// ~153MB compulsory traffic, invariant to store policy / MLP / barriers /
// occupancy / read-segment size (64B..1280B); same-capture fillBuffer hit
// 6.6 TB/s. Surviving theory: memory-issue duty cycle -- the shared
// load/compute/store skeleton never overlaps tile k+1's reads with tile
// k's compute, so per-CU in-flight bytes average ~4KB (need ~9KB).
// Fix: 768 blocks x 256 threads, 5 tiles per block (exactly 3 blocks/CU,
// 15 tiles/CU, no tail). Per iteration: issue next tile's 7 loads into a
// second register set, transform current -> LDS -> RAW s_barrier with
// lgkmcnt(0) only (no vmcnt drain -- prefetch stays in flight across the
// barrier, AITER-style), contiguous b128 reads -> second barrier ->
// contiguous cached stores. Tell: VGPR ~100 (two live tile sets).

#define A_       3
#define H_       80
#define W_       80
#define CH_      85                 // 5 + 80 classes
#define HW_      (H_ * W_)          // 6400
#define TILEF_   (CH_ * W_)         // 6800 floats per tile (ba,y)
#define QT_      (TILEF_ / 4)       // 1700 f32x4 quads
#define THREADS_ 256
#define NIT_     7                  // ceil(1700/256)
#define GRID_    768                // 3 blocks/CU exactly
#define TPB_     5                  // tiles per block: 768*5 = 3840

typedef float f32x4 __attribute__((ext_vector_type(4)));

__device__ __forceinline__ float fast_sigmoid(float x) {
    return __builtin_amdgcn_rcpf(1.0f + __expf(-x));
}

__global__ __launch_bounds__(THREADS_) void yolo_head_kernel(
    const float* __restrict__ in,
    const float* __restrict__ anchors,
    float* __restrict__ out)
{
    __shared__ float lds[TILEF_];

    const int t = threadIdx.x;

    // Per-thread quad geometry (identical for every tile): i = ch*20 + xq.
    int chv[NIT_], xqv[NIT_];
#pragma unroll
    for (int k = 0; k < NIT_; ++k) {
        int i = k * THREADS_ + t;
        i = (i < QT_) ? i : (QT_ - 1);
        chv[k] = i / 20;
        xqv[k] = i - 20 * chv[k];
    }

    f32x4 v[NIT_], v2[NIT_];

    // Prologue: load tile 0 of this block.
    {
        const int tile = blockIdx.x;
        const int y_   = tile % H_;
        const int ba_  = tile / H_;
        const float* r_ = in + (size_t)(ba_ * CH_) * HW_ + y_ * W_;
#pragma unroll
        for (int k = 0; k < NIT_; ++k)
            v[k] = *(const f32x4*)(r_ + chv[k] * HW_ + 4 * xqv[k]);
    }

    for (int it = 0; it < TPB_; ++it) {
        const int cur = blockIdx.x + it * GRID_;

        // ---- Prefetch next tile into v2 (uniform branch; pinned) ----
        if (it < TPB_ - 1) {
            const int nt  = cur + GRID_;
            const int y_  = nt % H_;
            const int ba_ = nt / H_;
            const float* r_ = in + (size_t)(ba_ * CH_) * HW_ + y_ * W_;
#pragma unroll
            for (int k = 0; k < NIT_; ++k)
                v2[k] = *(const f32x4*)(r_ + chv[k] * HW_ + 4 * xqv[k]);
        }
        __builtin_amdgcn_sched_barrier(0);

        // ---- Transform current tile -> LDS transposed [80 x][85 ch] ----
        const int y  = cur % H_;
        const int ba = cur / H_;
        const int a  = ba % A_;
        const float aw = anchors[2 * a];
        const float ah = anchors[2 * a + 1];
        const float fy = (float)y;

#pragma unroll
        for (int k = 0; k < NIT_; ++k) {
            int i = k * THREADS_ + t;
            if (i < QT_) {
                int ch = chv[k];
                int xq = xqv[k];
                f32x4 d = v[k];
                float r[4];
                if (ch >= 4) {
                    r[0] = fast_sigmoid(d.x);
                    r[1] = fast_sigmoid(d.y);
                    r[2] = fast_sigmoid(d.z);
                    r[3] = fast_sigmoid(d.w);
                } else if (ch == 0) {
                    float xg = (float)(4 * xq);
                    r[0] = (fast_sigmoid(d.x) + xg)        * 8.0f;  // px
                    r[1] = (fast_sigmoid(d.y) + xg + 1.0f) * 8.0f;
                    r[2] = (fast_sigmoid(d.z) + xg + 2.0f) * 8.0f;
                    r[3] = (fast_sigmoid(d.w) + xg + 3.0f) * 8.0f;
                } else if (ch == 1) {
                    r[0] = (fast_sigmoid(d.x) + fy) * 8.0f;         // py
                    r[1] = (fast_sigmoid(d.y) + fy) * 8.0f;
                    r[2] = (fast_sigmoid(d.z) + fy) * 8.0f;
                    r[3] = (fast_sigmoid(d.w) + fy) * 8.0f;
                } else {
                    float s = (ch == 2) ? aw : ah;                  // pw / ph
                    r[0] = __expf(fminf(fmaxf(d.x, -16.0f), 16.0f)) * s;
                    r[1] = __expf(fminf(fmaxf(d.y, -16.0f), 16.0f)) * s;
                    r[2] = __expf(fminf(fmaxf(d.z, -16.0f), 16.0f)) * s;
                    r[3] = __expf(fminf(fmaxf(d.w, -16.0f), 16.0f)) * s;
                }
                int base = 4 * xq * CH_ + ch;   // lds[(4*xq+j)*85 + ch]
#pragma unroll
                for (int j = 0; j < 4; ++j)
                    lds[base + j * CH_] = r[j];
            }
        }
        // LDS writes visible to all waves; do NOT drain vmcnt (prefetch
        // must stay in flight across the barrier).
        asm volatile("s_waitcnt lgkmcnt(0)" ::: "memory");
        __builtin_amdgcn_s_barrier();

        // ---- Contiguous LDS read -> contiguous cached stores ----
        const f32x4* lds4 = (const f32x4*)lds;
        f32x4 o[NIT_];
#pragma unroll
        for (int k = 0; k < NIT_; ++k) {
            int c = k * THREADS_ + t;
            c = (c < QT_) ? c : (QT_ - 1);
            o[k] = lds4[c];
        }
        // All reads done before next iteration's LDS writes (WAR guard).
        asm volatile("s_waitcnt lgkmcnt(0)" ::: "memory");
        __builtin_amdgcn_s_barrier();
        __builtin_amdgcn_sched_barrier(0);

        f32x4* out4 = (f32x4*)(out + (size_t)cur * TILEF_);
#pragma unroll
        for (int k = 0; k < NIT_; ++k) {
            int c = k * THREADS_ + t;
            if (c < QT_)
                out4[c] = o[k];
        }

        // Rotate prefetched tile into place (compiler's auto vmcnt wait
        // for v2 lands here, after the stores were issued).
#pragma unroll
        for (int k = 0; k < NIT_; ++k)
            v[k] = v2[k];
    }
}

extern "C" void kernel_launch(void* const* d_in, const int* in_sizes, int n_in,
                              void* d_out, int out_size, void* d_ws, size_t ws_size,
                              hipStream_t stream) {
    const float* in      = (const float*)d_in[0];   // (16, 255, 80, 80) fp32
    const float* anchors = (const float*)d_in[1];   // (3, 2) fp32
    float*       out     = (float*)d_out;           // (16, 19200, 85) fp32

    yolo_head_kernel<<<GRID_, THREADS_, 0, stream>>>(in, anchors, out);
}

// Round 10
// 179.770 us; speedup vs baseline: 1.0500x; 1.0500x over previous
//
#include <hip/hip_runtime.h>

// YOLOv7 P3 head (stride 8): B=16, A=3, NC=80, H=W=80.
// Input  (b, a*85, h, w) channel-major fp32.
// Output (b, a*h*w, 85)  fp32: [px,py,pw,ph,conf,cls*80].
//
// v11 = v5 + NONTEMPORAL LOADS (single-variable flip).
// Ledger: store policy, reg-MLP depth, barriers, occupancy, read segments
// 64B-1280B, persistent+prefetch pipelining -- all flat at 62-66us,
// ~2.5 TB/s for ~160MB compulsory traffic; same-capture fill=6.6 TB/s,
// copy=6.3 TB/s. global_load_lds DMA path kills the container (2 strikes,
// abandoned). Surviving mechanism: zero-reuse READ allocations thrash the
// 4MB/XCD L2 against the 102MB/iter write stream, fragmenting write
// combining toward EA. nt loads = no-allocate reads, L2 left to writes.
//
// One block per (b,a,y): output block = 6800 contiguous floats at bid*6800.
// 512 threads/block: 4 blocks x 8 waves = 32 waves/CU.

#define A_    3
#define H_    80
#define W_    80
#define CH_   85            // 5 + 80 classes
#define TILE_ (CH_ * W_)    // 6800 floats per (b,a,y)
#define VEC_  (TILE_ / 4)   // 1700 float4

typedef float f32x4 __attribute__((ext_vector_type(4)));

__device__ __forceinline__ float fast_sigmoid(float x) {
    return __builtin_amdgcn_rcpf(1.0f + __expf(-x));
}

__global__ __launch_bounds__(512) void yolo_head_kernel(
    const float* __restrict__ in,
    const float* __restrict__ anchors,
    float* __restrict__ out)
{
    __shared__ float lds[TILE_];

    const int bid = blockIdx.x;        // (b*3 + a)*80 + y
    const int y   = bid % H_;
    const int ba  = bid / H_;          // b*3 + a
    const int a   = ba % A_;

    const float aw = anchors[2 * a];
    const float ah = anchors[2 * a + 1];
    const float fy = (float)y;
    const int   t  = threadIdx.x;

    // ---- Phase 1a: 4 nontemporal f32x4 loads (no L1/L2 allocation) ----
    // in[(ba*85 + ch)*6400 + y*80 + x], x = 4*xq + j
    const float* in_row = in + (size_t)(ba * CH_) * (H_ * W_) + y * W_;

    f32x4 v[4];
    int   chv[4], xqv[4];
#pragma unroll
    for (int k = 0; k < 4; ++k) {
        int i = k * 512 + t;               // i = ch*20 + xq
        i = (i < VEC_) ? i : (VEC_ - 1);   // clamp: tail lanes re-load last quad
        int ch = i / 20;
        int xq = i - ch * 20;
        chv[k] = ch;
        xqv[k] = xq;
        v[k] = __builtin_nontemporal_load(
                   (const f32x4*)(in_row + ch * (H_ * W_) + 4 * xq));
    }
    __builtin_amdgcn_sched_barrier(0);

    // ---- Phase 1b: transform -> LDS (x-major, output order lds[x*85+ch])
#pragma unroll
    for (int k = 0; k < 4; ++k) {
        int i = k * 512 + t;
        if (i < VEC_) {
            int ch = chv[k];
            int xq = xqv[k];
            f32x4 w = v[k];
            float r[4];
            if (ch >= 4) {
                r[0] = fast_sigmoid(w.x);
                r[1] = fast_sigmoid(w.y);
                r[2] = fast_sigmoid(w.z);
                r[3] = fast_sigmoid(w.w);
            } else if (ch == 0) {
                float x0 = (float)(4 * xq);
                r[0] = (fast_sigmoid(w.x) + x0)        * 8.0f;  // px
                r[1] = (fast_sigmoid(w.y) + x0 + 1.0f) * 8.0f;
                r[2] = (fast_sigmoid(w.z) + x0 + 2.0f) * 8.0f;
                r[3] = (fast_sigmoid(w.w) + x0 + 3.0f) * 8.0f;
            } else if (ch == 1) {
                r[0] = (fast_sigmoid(w.x) + fy) * 8.0f;         // py
                r[1] = (fast_sigmoid(w.y) + fy) * 8.0f;
                r[2] = (fast_sigmoid(w.z) + fy) * 8.0f;
                r[3] = (fast_sigmoid(w.w) + fy) * 8.0f;
            } else {
                float s = (ch == 2) ? aw : ah;                  // pw / ph
                r[0] = __expf(fminf(fmaxf(w.x, -16.0f), 16.0f)) * s;
                r[1] = __expf(fminf(fmaxf(w.y, -16.0f), 16.0f)) * s;
                r[2] = __expf(fminf(fmaxf(w.z, -16.0f), 16.0f)) * s;
                r[3] = __expf(fminf(fmaxf(w.w, -16.0f), 16.0f)) * s;
            }
            int base = 4 * xq * CH_ + ch;   // lds[(4*xq+j)*85 + ch]
#pragma unroll
            for (int j = 0; j < 4; ++j)
                lds[base + j * CH_] = r[j];
        }
    }
    __syncthreads();

    // ---- Phase 2: LDS -> out, contiguous 16B cached stores ----
    f32x4*       out4 = (f32x4*)(out + (size_t)bid * TILE_);
    const f32x4* lds4 = (const f32x4*)lds;

    f32x4 o[4];
#pragma unroll
    for (int k = 0; k < 4; ++k) {
        int c = k * 512 + t;
        c = (c < VEC_) ? c : (VEC_ - 1);
        o[k] = lds4[c];
    }
    __builtin_amdgcn_sched_barrier(0);
#pragma unroll
    for (int k = 0; k < 4; ++k) {
        int c = k * 512 + t;
        if (c < VEC_) {
            out4[c] = o[k];
        }
    }
}

extern "C" void kernel_launch(void* const* d_in, const int* in_sizes, int n_in,
                              void* d_out, int out_size, void* d_ws, size_t ws_size,
                              hipStream_t stream) {
    const float* in      = (const float*)d_in[0];   // (16, 255, 80, 80) fp32
    const float* anchors = (const float*)d_in[1];   // (3, 2) fp32
    float*       out     = (float*)d_out;           // (16, 19200, 85) fp32

    const int blocks = 16 * A_ * H_;                // 3840: one per (b,a,y)
    yolo_head_kernel<<<blocks, 512, 0, stream>>>(in, anchors, out);
}

// Round 11
// 179.166 us; speedup vs baseline: 1.0536x; 1.0034x over previous
//
#include <hip/hip_runtime.h>

// YOLOv7 P3 head (stride 8): B=16, A=3, NC=80, H=W=80.
// Input  (b, a*85, h, w) channel-major fp32.
// Output (b, a*h*w, 85)  fp32: [px,py,pw,ph,conf,cls*80].
//
// v12 = v7 (y-pair, 640B read segments) + NONTEMPORAL LOADS.
// v11 (nt loads alone, 320B segments) was the first lever to move time in
// 11 rounds: kernel dropped below the 62us fill dispatches (~58us est).
// Mechanism: zero-reuse read allocations were thrashing the 4MB/XCD L2
// against the 102MB write stream; no-allocate reads restore write
// combining. Now reads hit DRAM directly -> page-granule efficiency can
// matter (it couldn't in v6-v8 when L2/L3 buffered reads). This round:
// same nt-load policy, read segments 320B -> 640B (y-pair blocks).
// Block = (ba, y/2): 1920 blocks, 512 threads, LDS 54.4KB (2 blocks/CU,
// 16 waves/CU -- occupancy proven non-binding 9-18 waves).

#define A_     3
#define H_     80
#define W_     80
#define CH_    85                   // 5 + 80 classes
#define HW_    (H_ * W_)            // 6400
#define YPB_   2                    // y rows per block
#define TILEF_ (CH_ * W_ * YPB_)    // 13600 floats
#define QT_    (TILEF_ / 4)         // 3400 f32x4 quads
#define NIT_   7                    // ceil(3400 / 512)

typedef float f32x4 __attribute__((ext_vector_type(4)));

__device__ __forceinline__ float fast_sigmoid(float x) {
    return __builtin_amdgcn_rcpf(1.0f + __expf(-x));
}

__global__ __launch_bounds__(512) void yolo_head_kernel(
    const float* __restrict__ in,
    const float* __restrict__ anchors,
    float* __restrict__ out)
{
    __shared__ float lds[TILEF_];   // 54400 B

    const int bid = blockIdx.x;        // ba*40 + y2
    const int y2  = bid % (H_ / YPB_);
    const int ba  = bid / (H_ / YPB_); // b*3 + a
    const int a   = ba % A_;
    const int y0  = y2 * YPB_;

    const float aw = anchors[2 * a];
    const float ah = anchors[2 * a + 1];
    const int   t  = threadIdx.x;

    // ---- Phase 1a: 7 clamped NONTEMPORAL f32x4 loads, 640B segments ----
    // quad i = ch*40 + xq, xq in [0,40): 160 floats = rows y0,y0+1 of ch.
    const float* in_base = in + (size_t)(ba * CH_) * HW_ + y0 * W_;

    f32x4 v[NIT_];
#pragma unroll
    for (int k = 0; k < NIT_; ++k) {
        int i = k * 512 + t;
        i = (i < QT_) ? i : (QT_ - 1);   // clamp: tail lanes re-load last quad
        int ch = i / 40;
        int xq = i - ch * 40;
        v[k] = __builtin_nontemporal_load(
                   (const f32x4*)(in_base + ch * HW_ + 4 * xq));
    }
    __builtin_amdgcn_sched_barrier(0);

    // ---- Phase 1b: transform -> LDS transposed [2 rows][80 x][85 ch] ----
#pragma unroll
    for (int k = 0; k < NIT_; ++k) {
        int i = k * 512 + t;
        if (i < QT_) {
            int ch = i / 40;
            int xq = i - ch * 40;
            int r  = (xq >= 20);             // quads don't straddle rows (80%4==0)
            int xb = 4 * xq - 80 * r;        // x of elem j: xb + j
            f32x4 d = v[k];
            float rr[4];
            if (ch >= 4) {
                rr[0] = fast_sigmoid(d.x);
                rr[1] = fast_sigmoid(d.y);
                rr[2] = fast_sigmoid(d.z);
                rr[3] = fast_sigmoid(d.w);
            } else if (ch == 0) {
                float xg = (float)xb;
                rr[0] = (fast_sigmoid(d.x) + xg)        * 8.0f;  // px
                rr[1] = (fast_sigmoid(d.y) + xg + 1.0f) * 8.0f;
                rr[2] = (fast_sigmoid(d.z) + xg + 2.0f) * 8.0f;
                rr[3] = (fast_sigmoid(d.w) + xg + 3.0f) * 8.0f;
            } else if (ch == 1) {
                float fy = (float)(y0 + r);
                rr[0] = (fast_sigmoid(d.x) + fy) * 8.0f;         // py
                rr[1] = (fast_sigmoid(d.y) + fy) * 8.0f;
                rr[2] = (fast_sigmoid(d.z) + fy) * 8.0f;
                rr[3] = (fast_sigmoid(d.w) + fy) * 8.0f;
            } else {
                float s = (ch == 2) ? aw : ah;                   // pw / ph
                rr[0] = __expf(fminf(fmaxf(d.x, -16.0f), 16.0f)) * s;
                rr[1] = __expf(fminf(fmaxf(d.y, -16.0f), 16.0f)) * s;
                rr[2] = __expf(fminf(fmaxf(d.z, -16.0f), 16.0f)) * s;
                rr[3] = __expf(fminf(fmaxf(d.w, -16.0f), 16.0f)) * s;
            }
            // lds[r*6800 + (xb+j)*85 + ch]
            int base = r * (CH_ * W_) + xb * CH_ + ch;
#pragma unroll
            for (int j = 0; j < 4; ++j)
                lds[base + j * CH_] = rr[j];
        }
    }
    __syncthreads();

    // ---- Phase 2: contiguous LDS read -> 27.2KB contiguous cached stores ----
    // out base: (ba*6400 + y0*80) * 85 floats; 13600 floats contiguous.
    f32x4*       out4 = (f32x4*)(out + (size_t)(ba * HW_ + y0 * W_) * CH_);
    const f32x4* lds4 = (const f32x4*)lds;

    f32x4 o[NIT_];
#pragma unroll
    for (int k = 0; k < NIT_; ++k) {
        int c = k * 512 + t;
        c = (c < QT_) ? c : (QT_ - 1);
        o[k] = lds4[c];
    }
    __builtin_amdgcn_sched_barrier(0);
#pragma unroll
    for (int k = 0; k < NIT_; ++k) {
        int c = k * 512 + t;
        if (c < QT_) {
            out4[c] = o[k];
        }
    }
}

extern "C" void kernel_launch(void* const* d_in, const int* in_sizes, int n_in,
                              void* d_out, int out_size, void* d_ws, size_t ws_size,
                              hipStream_t stream) {
    const float* in      = (const float*)d_in[0];   // (16, 255, 80, 80) fp32
    const float* anchors = (const float*)d_in[1];   // (3, 2) fp32
    float*       out     = (float*)d_out;           // (16, 19200, 85) fp32

    const int blocks = 16 * A_ * (H_ / YPB_);       // 1920: one per (b,a,y-pair)
    yolo_head_kernel<<<blocks, 512, 0, stream>>>(in, anchors, out);
}